// Round 4
// baseline (251.506 us; speedup 1.0000x reference)
//
#include <hip/hip_runtime.h>
#include <stdint.h>

#define EPSF 1e-5f
#define LOG2E 1.4426950408889634f

typedef _Float16 h2 __attribute__((ext_vector_type(2)));
union UH2 { uint32_t u; h2 h; };

__device__ __forceinline__ uint32_t pkh(float a, float b){
  UH2 c; c.h.x = (_Float16)a; c.h.y = (_Float16)b; return c.u;
}
__device__ __forceinline__ h2 ash2(uint32_t u){ UH2 c; c.u = u; return c.h; }

#if __has_builtin(__builtin_amdgcn_fdot2)
__device__ __forceinline__ float fdot2u(uint32_t a, uint32_t b, float c){
  return __builtin_amdgcn_fdot2(ash2(a), ash2(b), c, false);
}
#else
__device__ __forceinline__ float fdot2u(uint32_t a, uint32_t b, float c){
  h2 x = ash2(a), y = ash2(b);
  return fmaf((float)x.y, (float)y.y, fmaf((float)x.x, (float)y.x, c));
}
#endif

// ---------------- rel_enc packing (both tables, one launch) ----------------
// rqk[j] = {qe01, qe23, keR01, keR23} f16-packed (keR[j] = ke[NJ-1-j])
// rve[j] = {ve01, ve23, ve45, ve67} f16-packed
__global__ void k_relpack(const float* __restrict__ relH, const float* __restrict__ relW,
                          uint4* __restrict__ rqkH, uint4* __restrict__ rveH,
                          uint4* __restrict__ rqkW, uint4* __restrict__ rveW) {
  int NJ = blockIdx.x ? 255 : 511;
  const float* rel = blockIdx.x ? relW : relH;
  uint4* rqk = blockIdx.x ? rqkW : rqkH;
  uint4* rve = blockIdx.x ? rveW : rveH;
  int j = threadIdx.x;
  if (j >= NJ) return;
  const float* q = rel;
  const float* k = rel + 4*NJ;
  const float* v = rel + 8*NJ;
  int jr = NJ-1-j;
  uint4 a;
  a.x = pkh(q[0*NJ+j], q[1*NJ+j]);
  a.y = pkh(q[2*NJ+j], q[3*NJ+j]);
  a.z = pkh(k[0*NJ+jr], k[1*NJ+jr]);
  a.w = pkh(k[2*NJ+jr], k[3*NJ+jr]);
  rqk[j] = a;
  uint4 b;
  b.x = pkh(v[0*NJ+j], v[1*NJ+j]);
  b.y = pkh(v[2*NJ+j], v[3*NJ+j]);
  b.z = pkh(v[4*NJ+j], v[5*NJ+j]);
  b.w = pkh(v[6*NJ+j], v[7*NJ+j]);
  rve[j] = b;
}

// ---------------- conv1 + bn + relu : NCHW in -> NHWC out (coalesced both sides) ----------------
__global__ __launch_bounds__(256)
void k_conv1(const float* __restrict__ in, const float* __restrict__ w,
             const float* __restrict__ bn, float* __restrict__ out) {
  __shared__ float L[64*65];
  int tid = threadIdx.x;
  int p0 = blockIdx.x * 64;
  int lane = tid & 63, wv = tid >> 6;
  // stage NCHW tile: L[c*64+p], coalesced dword loads (lane = p)
  #pragma unroll
  for (int rr = 0; rr < 16; ++rr) {
    int c = wv*16 + rr;
    L[c*64 + lane] = in[(size_t)c*32768 + p0 + lane];
  }
  __syncthreads();
  float xv[64];
  #pragma unroll
  for (int c = 0; c < 64; ++c) xv[c] = L[c*64 + lane];   // stride-1 across lanes
  float val[16];
  #pragma unroll
  for (int r = 0; r < 16; ++r) {
    int o = wv*16 + r;                       // wave-uniform -> s_load weights
    const float* wr = w + o*64;
    float acc = 0.f;
    #pragma unroll
    for (int c = 0; c < 64; ++c) acc = fmaf(wr[c], xv[c], acc);
    float s = bn[o] * rsqrtf(bn[192+o] + EPSF);
    val[r] = fmaxf(fmaf(acc, s, fmaf(-bn[128+o], s, bn[64+o])), 0.f);
  }
  __syncthreads();
  #pragma unroll
  for (int r = 0; r < 16; ++r) L[lane*65 + wv*16 + r] = val[r];  // (p+o)%32 banks
  __syncthreads();
  // contiguous 16KB block write, fully coalesced float4
  float4* dst = (float4*)(out + (size_t)p0*64);
  #pragma unroll
  for (int k = 0; k < 4; ++k) {
    int f4 = tid + k*256;
    int f = f4*4; int p = f >> 6, o = f & 63;
    float4 v;
    v.x = L[p*65+o]; v.y = L[p*65+o+1]; v.z = L[p*65+o+2]; v.w = L[p*65+o+3];
    dst[f4] = v;
  }
}

// ---------------- kqv projection + bn -> f16-packed K/Q/V ----------------
// block: (n, y-block of 64), 512 thr = 8 heads x 64 y. Row yy at ((y0+yy)*RS+n*CS)*64.
template<int LEN, int RS, int CS>
__global__ __launch_bounds__(512)
void k_kqv(const float* __restrict__ in, const float* __restrict__ w,
           const float* __restrict__ bn, uint4* __restrict__ kvV,
           uint2* __restrict__ kvK, uint2* __restrict__ qb) {
  __shared__ float L[64*65];
  int tid = threadIdx.x;
  int n = blockIdx.x;
  int y0 = blockIdx.y * 64;
  // stage 64 rows, each row = 64 contiguous floats (wave-per-row coalesced)
  #pragma unroll
  for (int rr = 0; rr < 8; ++rr) {
    int idx = tid + rr*512;
    int yy = idx >> 6, c = idx & 63;
    L[yy*65 + c] = in[((size_t)(y0+yy)*RS + (size_t)n*CS)*64 + c];
  }
  __syncthreads();
  int hd = tid >> 6, yy = tid & 63;        // hd wave-uniform
  float xv[64];
  #pragma unroll
  for (int c = 0; c < 64; ++c) xv[c] = L[yy*65 + c];   // (yy+c)%32 banks
  float val[16];
  #pragma unroll
  for (int r = 0; r < 16; ++r) {
    int o = hd*16 + r;
    const float* wr = w + o*64;
    float acc = 0.f;
    #pragma unroll
    for (int c = 0; c < 64; ++c) acc = fmaf(wr[c], xv[c], acc);
    float s = bn[o] * rsqrtf(bn[384+o] + EPSF);
    val[r] = fmaf(acc, s, fmaf(-bn[256+o], s, bn[128+o]));
  }
  size_t base = ((size_t)n*8 + hd)*LEN + (y0 + yy);
  kvK[base] = make_uint2(pkh(val[0],val[1]), pkh(val[2],val[3]));
  qb[base]  = make_uint2(pkh(val[4],val[5]), pkh(val[6],val[7]));
  kvV[base] = make_uint4(pkh(val[8],val[9]),  pkh(val[10],val[11]),
                         pkh(val[12],val[13]), pkh(val[14],val[15]));
}

// ---------------- axial attention core (v4: f16 + dot2) ----------------
template<int LEN, bool RELUO, int XS, int NS>
__global__ __launch_bounds__(LEN, 2)
void k_attn3(const uint4* __restrict__ kvV, const uint2* __restrict__ kvK,
             const uint2* __restrict__ qb, const uint4* __restrict__ rqk,
             const uint4* __restrict__ rve, const float* __restrict__ lbn,
             float* __restrict__ out) {
  constexpr int NJ = 2*LEN-1;
  constexpr int HALF = LEN/2;
  constexpr int CH = 4;
  int n  = blockIdx.x >> 3;
  int hd = blockIdx.x & 7;
  int t  = threadIdx.x;

  __shared__ __align__(16) char pool[(size_t)LEN*24 + (size_t)NJ*32];
  uint2* sK  = (uint2*)(pool);                          // [LEN] k01,k23 f16
  uint4* sV  = (uint4*)(pool + (size_t)LEN*8);          // [LEN] v0..7 f16
  uint4* sT  = (uint4*)(pool + (size_t)LEN*24);         // [NJ] qe01,qe23,keR01,keR23
  uint4* sVE = (uint4*)(pool + (size_t)LEN*24 + (size_t)NJ*16); // [NJ] ve0..7 f16

  size_t kvbase = ((size_t)n*8 + hd)*LEN;
  sK[t] = kvK[kvbase + t];
  sV[t] = kvV[kvbase + t];
  for (int j = t; j < NJ; j += LEN) { sT[j] = rqk[j]; sVE[j] = rve[j]; }

  float A0,A1,A2,Bc;
  {
    int c0 = hd, c1 = 8+hd, c2 = 16+hd;
    float s0 = lbn[c0]*rsqrtf(lbn[72+c0]+EPSF);
    float s1 = lbn[c1]*rsqrtf(lbn[72+c1]+EPSF);
    float s2 = lbn[c2]*rsqrtf(lbn[72+c2]+EPSF);
    float t0 = fmaf(-lbn[48+c0], s0, lbn[24+c0]);
    float t1 = fmaf(-lbn[48+c1], s1, lbn[24+c1]);
    float t2 = fmaf(-lbn[48+c2], s2, lbn[24+c2]);
    A0 = s0*LOG2E; A1 = s1*LOG2E; A2 = s2*LOG2E; Bc = (t0+t1+t2)*LOG2E;
  }

  int g  = t / HALF;
  int tl = t % HALF;
  int y0 = g * HALF;

  uint2 q[2];
  q[0] = qb[kvbase + tl];
  q[1] = qb[kvbase + tl + HALF];

  float m[2], ss[2], acc[2][8], lr[2][CH];
  #pragma unroll
  for (int i=0;i<2;++i){ m[i]=-3.0e38f; ss[i]=0.f;
    #pragma unroll
    for(int d=0;d<8;++d) acc[i][d]=0.f; }

  __syncthreads();

  for (int yc = 0; yc < HALF; yc += CH) {
    // ---- pass A: logits via v_dot2_f32_f16 ----
    #pragma unroll
    for (int c = 0; c < CH; ++c) {
      int y = y0 + yc + c;
      uint2 kk = sK[y];   // broadcast
      #pragma unroll
      for (int i = 0; i < 2; ++i) {
        int j = y - (tl + i*HALF) + (LEN-1);
        uint4 qe = sT[j];
        float qk = fdot2u(q[i].x, kk.x, fdot2u(q[i].y, kk.y, 0.f));
        float qr = fdot2u(q[i].x, qe.x, fdot2u(q[i].y, qe.y, 0.f));
        float kr = fdot2u(kk.x, qe.z, fdot2u(kk.y, qe.w, 0.f));
        lr[i][c] = fmaf(qk,A0, fmaf(qr,A1, fmaf(kr,A2, Bc)));
      }
    }
    // ---- branchless chunk rescale ----
    #pragma unroll
    for (int i = 0; i < 2; ++i) {
      float cm = fmaxf(fmaxf(lr[i][0], lr[i][1]), fmaxf(lr[i][2], lr[i][3]));
      float mn = fmaxf(m[i], cm);
      float sc = __builtin_amdgcn_exp2f(m[i] - mn);
      m[i] = mn; ss[i] *= sc;
      #pragma unroll
      for (int d = 0; d < 8; ++d) acc[i][d] *= sc;
    }
    // ---- pass B: exp + accumulate (pk_add_f16 + fma_mix) ----
    #pragma unroll
    for (int c = 0; c < CH; ++c) {
      int y = y0 + yc + c;
      uint4 vv = sV[y];   // broadcast
      #pragma unroll
      for (int i = 0; i < 2; ++i) {
        int j = y - (tl + i*HALF) + (LEN-1);
        uint4 ve = sVE[j];
        float e = __builtin_amdgcn_exp2f(lr[i][c] - m[i]);
        ss[i] += e;
        h2 s0 = ash2(vv.x) + ash2(ve.x);
        h2 s1 = ash2(vv.y) + ash2(ve.y);
        h2 s2 = ash2(vv.z) + ash2(ve.z);
        h2 s3 = ash2(vv.w) + ash2(ve.w);
        acc[i][0] = fmaf(e, (float)s0.x, acc[i][0]);
        acc[i][1] = fmaf(e, (float)s0.y, acc[i][1]);
        acc[i][2] = fmaf(e, (float)s1.x, acc[i][2]);
        acc[i][3] = fmaf(e, (float)s1.y, acc[i][3]);
        acc[i][4] = fmaf(e, (float)s2.x, acc[i][4]);
        acc[i][5] = fmaf(e, (float)s2.y, acc[i][5]);
        acc[i][6] = fmaf(e, (float)s3.x, acc[i][6]);
        acc[i][7] = fmaf(e, (float)s3.y, acc[i][7]);
      }
    }
  }

  // ---- merge the two y-groups via LDS ----
  __syncthreads();
  float4* M0 = (float4*)(pool);                    // [HALF*2] acc0..3
  float4* M1 = (float4*)(pool + (size_t)HALF*32);  // [HALF*2] acc4..7
  float2* MS = (float2*)(pool + (size_t)HALF*64);  // [HALF*2] (m, ss)
  if (g == 1) {
    #pragma unroll
    for (int i = 0; i < 2; ++i) {
      M0[tl*2+i] = make_float4(acc[i][0],acc[i][1],acc[i][2],acc[i][3]);
      M1[tl*2+i] = make_float4(acc[i][4],acc[i][5],acc[i][6],acc[i][7]);
      MS[tl*2+i] = make_float2(m[i], ss[i]);
    }
  }
  __syncthreads();
  if (g == 0) {
    #pragma unroll
    for (int i = 0; i < 2; ++i) {
      float2 os = MS[tl*2+i];
      float4 a0 = M0[tl*2+i];
      float4 a1 = M1[tl*2+i];
      float M  = fmaxf(m[i], os.x);
      float w0 = __builtin_amdgcn_exp2f(m[i] - M);
      float w1 = __builtin_amdgcn_exp2f(os.x - M);
      float inv = 1.0f / (ss[i]*w0 + os.y*w1);
      int x = tl + i*HALF;
      float* dst = out + ((size_t)x*XS + (size_t)n*NS)*64 + hd*8;
      float4 lo, hi;
      lo.x = (acc[i][0]*w0 + a0.x*w1)*inv;
      lo.y = (acc[i][1]*w0 + a0.y*w1)*inv;
      lo.z = (acc[i][2]*w0 + a0.z*w1)*inv;
      lo.w = (acc[i][3]*w0 + a0.w*w1)*inv;
      hi.x = (acc[i][4]*w0 + a1.x*w1)*inv;
      hi.y = (acc[i][5]*w0 + a1.y*w1)*inv;
      hi.z = (acc[i][6]*w0 + a1.z*w1)*inv;
      hi.w = (acc[i][7]*w0 + a1.w*w1)*inv;
      if (RELUO) {
        lo.x=fmaxf(lo.x,0.f); lo.y=fmaxf(lo.y,0.f); lo.z=fmaxf(lo.z,0.f); lo.w=fmaxf(lo.w,0.f);
        hi.x=fmaxf(hi.x,0.f); hi.y=fmaxf(hi.y,0.f); hi.z=fmaxf(hi.z,0.f); hi.w=fmaxf(hi.w,0.f);
      }
      *(float4*)dst = lo;
      *((float4*)dst + 1) = hi;
    }
  }
}

// ---------------- conv3 + bn + residual + relu : NHWC in -> NCHW out ----------------
__global__ __launch_bounds__(256)
void k_conv3(const float* __restrict__ in, const float* __restrict__ w,
             const float* __restrict__ bn, const float* __restrict__ resid,
             float* __restrict__ out) {
  __shared__ float L[64*65];
  int tid = threadIdx.x;
  int p0 = blockIdx.x * 64;
  // stage contiguous 16KB NHWC tile, coalesced float4
  const float4* src = (const float4*)(in + (size_t)p0*64);
  #pragma unroll
  for (int k = 0; k < 4; ++k) {
    int f4 = tid + k*256;
    float4 v = src[f4];
    int f = f4*4; int p = f >> 6, o = f & 63;
    L[p*65+o] = v.x; L[p*65+o+1] = v.y; L[p*65+o+2] = v.z; L[p*65+o+3] = v.w;
  }
  __syncthreads();
  int lane = tid & 63, wv = tid >> 6;
  float xv[64];
  #pragma unroll
  for (int c = 0; c < 64; ++c) xv[c] = L[lane*65 + c];
  #pragma unroll
  for (int r = 0; r < 16; ++r) {
    int o = wv*16 + r;
    const float* wr = w + o*64;
    float acc = 0.f;
    #pragma unroll
    for (int c = 0; c < 64; ++c) acc = fmaf(wr[c], xv[c], acc);
    float s = bn[o] * rsqrtf(bn[192+o] + EPSF);
    float val = fmaf(acc, s, fmaf(-bn[128+o], s, bn[64+o]));
    size_t idx = (size_t)o*32768 + p0 + lane;
    out[idx] = fmaxf(val + resid[idx], 0.f);    // coalesced NCHW
  }
}

extern "C" void kernel_launch(void* const* d_in, const int* in_sizes, int n_in,
                              void* d_out, int out_size, void* d_ws, size_t ws_size,
                              hipStream_t stream) {
  const float* x         = (const float*)d_in[0];
  const float* conv1_w   = (const float*)d_in[1];
  const float* bn1       = (const float*)d_in[2];
  const float* kqv_w_h   = (const float*)d_in[3];
  const float* kqv_bn_h  = (const float*)d_in[4];
  const float* lbn_h     = (const float*)d_in[5];
  const float* rel_h     = (const float*)d_in[6];
  const float* kqv_w_w   = (const float*)d_in[7];
  const float* kqv_bn_w  = (const float*)d_in[8];
  const float* lbn_w     = (const float*)d_in[9];
  const float* rel_w     = (const float*)d_in[10];
  const float* conv3_w   = (const float*)d_in[11];
  const float* bn3       = (const float*)d_in[12];
  float* outp = (float*)d_out;
  char* ws = (char*)d_ws;

  float* A    = (float*)(ws);                    // 8 MiB
  uint4* kvV  = (uint4*)(ws + 8388608);          // 4 MiB
  uint2* kvK  = (uint2*)(ws + 12582912);         // 2 MiB
  uint2* qb   = (uint2*)(ws + 14680064);         // 2 MiB (f16-packed)
  uint4* rqkH = (uint4*)(ws + 18874368);
  uint4* rveH = (uint4*)(ws + 18882560);
  uint4* rqkW = (uint4*)(ws + 18890752);
  uint4* rveW = (uint4*)(ws + 18894848);

  k_relpack<<<2, 512, 0, stream>>>(rel_h, rel_w, rqkH, rveH, rqkW, rveW);

  // conv1 + bn1 + relu : x NCHW -> A NHWC
  k_conv1<<<512, 256, 0, stream>>>(x, conv1_w, bn1, A);

  // axial-H: n = w (128), seq = h (256)
  k_kqv<256,128,1><<<dim3(128,4), 512, 0, stream>>>(A, kqv_w_h, kqv_bn_h, kvV, kvK, qb);
  k_attn3<256,false,128,1><<<1024, 256, 0, stream>>>(kvV, kvK, qb, rqkH, rveH, lbn_h, A);

  // axial-W: n = h (256), seq = w (128); relu fused into output
  k_kqv<128,1,128><<<dim3(256,2), 512, 0, stream>>>(A, kqv_w_w, kqv_bn_w, kvV, kvK, qb);
  k_attn3<128,true,1,128><<<2048, 128, 0, stream>>>(kvV, kvK, qb, rqkW, rveW, lbn_w, A);

  // conv3 + bn3 + residual + relu : A NHWC -> out NCHW
  k_conv3<<<512, 256, 0, stream>>>(A, conv3_w, bn3, x, outp);
}

// Round 5
// 189.860 us; speedup vs baseline: 1.3247x; 1.3247x over previous
//
#include <hip/hip_runtime.h>
#include <stdint.h>

#define EPSF 1e-5f
#define LOG2E 1.4426950408889634f

__device__ __forceinline__ float bflo(uint32_t u){ union{uint32_t u;float f;}c; c.u=u<<16; return c.f; }
__device__ __forceinline__ float bfhi(uint32_t u){ union{uint32_t u;float f;}c; c.u=u&0xffff0000u; return c.f; }
// raw high-half: value == bf16_hi * (1+delta), |delta| <= 2^-7
__device__ __forceinline__ float bfhiraw(uint32_t u){ union{uint32_t u;float f;}c; c.u=u; return c.f; }
__device__ __forceinline__ uint32_t f2bf(float f){ union{float f;uint32_t u;}c; c.f=f; uint32_t u=c.u; return (u + 0x7fffu + ((u>>16)&1u)) >> 16; }
__device__ __forceinline__ uint32_t pk2(float a, float b){ return f2bf(a) | (f2bf(b)<<16); }

// ---------------- rel_enc packing (both tables, one launch, bf16) ----------------
// rqk[j] = {qe01, qe23, keR01, keR23} bf16-packed (keR[j] = ke[NJ-1-j])
// rve[j] = {ve01, ve23, ve45, ve67} bf16-packed
__global__ void k_relpack(const float* __restrict__ relH, const float* __restrict__ relW,
                          uint4* __restrict__ rqkH, uint4* __restrict__ rveH,
                          uint4* __restrict__ rqkW, uint4* __restrict__ rveW) {
  int NJ = blockIdx.x ? 255 : 511;
  const float* rel = blockIdx.x ? relW : relH;
  uint4* rqk = blockIdx.x ? rqkW : rqkH;
  uint4* rve = blockIdx.x ? rveW : rveH;
  int j = threadIdx.x;
  if (j >= NJ) return;
  const float* q = rel;
  const float* k = rel + 4*NJ;
  const float* v = rel + 8*NJ;
  int jr = NJ-1-j;
  uint4 a;
  a.x = pk2(q[0*NJ+j], q[1*NJ+j]);
  a.y = pk2(q[2*NJ+j], q[3*NJ+j]);
  a.z = pk2(k[0*NJ+jr], k[1*NJ+jr]);
  a.w = pk2(k[2*NJ+jr], k[3*NJ+jr]);
  rqk[j] = a;
  uint4 b;
  b.x = pk2(v[0*NJ+j], v[1*NJ+j]);
  b.y = pk2(v[2*NJ+j], v[3*NJ+j]);
  b.z = pk2(v[4*NJ+j], v[5*NJ+j]);
  b.w = pk2(v[6*NJ+j], v[7*NJ+j]);
  rve[j] = b;
}

// ---------------- conv1 + bn + relu : NCHW in -> NHWC out (coalesced both sides) ----------------
__global__ __launch_bounds__(256)
void k_conv1(const float* __restrict__ in, const float* __restrict__ w,
             const float* __restrict__ bn, float* __restrict__ out) {
  __shared__ float L[64*65];
  int tid = threadIdx.x;
  int p0 = blockIdx.x * 64;
  int lane = tid & 63;
  int wvs = __builtin_amdgcn_readfirstlane(tid >> 6);   // wave-uniform -> SGPR
  // stage NCHW tile: L[c*64+p], coalesced dword loads (lane = p)
  #pragma unroll
  for (int rr = 0; rr < 16; ++rr) {
    int c = wvs*16 + rr;
    L[c*64 + lane] = in[(size_t)c*32768 + p0 + lane];
  }
  __syncthreads();
  float xv[64];
  #pragma unroll
  for (int c = 0; c < 64; ++c) xv[c] = L[c*64 + lane];   // 2 lanes/bank: free
  float val[16];
  #pragma unroll
  for (int r = 0; r < 16; ++r) {
    int o = wvs*16 + r;                       // scalar -> s_load weights
    const float* wr = w + o*64;
    float acc = 0.f;
    #pragma unroll
    for (int c = 0; c < 64; ++c) acc = fmaf(wr[c], xv[c], acc);
    float s = bn[o] * rsqrtf(bn[192+o] + EPSF);
    val[r] = fmaxf(fmaf(acc, s, fmaf(-bn[128+o], s, bn[64+o])), 0.f);
  }
  __syncthreads();
  #pragma unroll
  for (int r = 0; r < 16; ++r) L[lane*65 + wvs*16 + r] = val[r];
  __syncthreads();
  // contiguous 16KB block write, fully coalesced float4
  float4* dst = (float4*)(out + (size_t)p0*64);
  #pragma unroll
  for (int k = 0; k < 4; ++k) {
    int f4 = tid + k*256;
    int f = f4*4; int p = f >> 6, o = f & 63;
    float4 v;
    v.x = L[p*65+o]; v.y = L[p*65+o+1]; v.z = L[p*65+o+2]; v.w = L[p*65+o+3];
    dst[f4] = v;
  }
}

// ---------------- kqv projection + bn -> bf16 K/V + f32 Q ----------------
// block: (n, y-block of 64), 512 thr = 8 heads x 64 y.
template<int LEN, int RS, int CS>
__global__ __launch_bounds__(512)
void k_kqv(const float* __restrict__ in, const float* __restrict__ w,
           const float* __restrict__ bn, uint4* __restrict__ kvV,
           uint2* __restrict__ kvK, float* __restrict__ qb) {
  __shared__ float L[64*65];
  int tid = threadIdx.x;
  int n = blockIdx.x;
  int y0 = blockIdx.y * 64;
  #pragma unroll
  for (int rr = 0; rr < 8; ++rr) {
    int idx = tid + rr*512;
    int yy = idx >> 6, c = idx & 63;
    L[yy*65 + c] = in[((size_t)(y0+yy)*RS + (size_t)n*CS)*64 + c];
  }
  __syncthreads();
  int hd = __builtin_amdgcn_readfirstlane(tid >> 6);   // scalar head index
  int yy = tid & 63;
  float xv[64];
  #pragma unroll
  for (int c = 0; c < 64; ++c) xv[c] = L[yy*65 + c];
  float val[16];
  #pragma unroll
  for (int r = 0; r < 16; ++r) {
    int o = hd*16 + r;
    const float* wr = w + o*64;               // scalar -> s_load
    float acc = 0.f;
    #pragma unroll
    for (int c = 0; c < 64; ++c) acc = fmaf(wr[c], xv[c], acc);
    float s = bn[o] * rsqrtf(bn[384+o] + EPSF);
    val[r] = fmaf(acc, s, fmaf(-bn[256+o], s, bn[128+o]));
  }
  size_t base = ((size_t)n*8 + hd)*LEN + (y0 + yy);
  kvK[base] = make_uint2(pk2(val[0],val[1]), pk2(val[2],val[3]));
  kvV[base] = make_uint4(pk2(val[8],val[9]),  pk2(val[10],val[11]),
                         pk2(val[12],val[13]), pk2(val[14],val[15]));
  float4 qq; qq.x = val[4]; qq.y = val[5]; qq.z = val[6]; qq.w = val[7];
  *(float4*)(qb + base*4) = qq;
}

// ---------------- axial attention core (v5: f32 core, G-way y-split) ----------------
// block = (n, head), T = LEN*G/2 threads: G y-groups of HALF lanes.
// thread (g, tl) handles x = tl, tl+HALF over y in [g*YR, (g+1)*YR).
// Chunked branchless online softmax, CH=4. G-way merge in LDS.
template<int LEN, int G, bool RELUO, int XS, int NS>
__global__ __launch_bounds__(LEN*G/2, 2)
void k_attn2(const uint4* __restrict__ kvV, const uint2* __restrict__ kvK,
             const float* __restrict__ qb, const uint4* __restrict__ rqk,
             const uint4* __restrict__ rve, const float* __restrict__ lbn,
             float* __restrict__ out) {
  constexpr int NJ = 2*LEN-1;
  constexpr int HALF = LEN/2;
  constexpr int T = LEN*G/2;
  constexpr int YR = LEN/G;
  constexpr int CH = 4;
  constexpr size_t S1 = (size_t)LEN*48 + (size_t)NJ*48;   // staging
  constexpr size_t S2 = (size_t)(G-1)*LEN*40;             // merge
  constexpr size_t PS = S1 > S2 ? S1 : S2;
  int n  = blockIdx.x >> 3;
  int hd = blockIdx.x & 7;
  int t  = threadIdx.x;

  __shared__ __align__(16) char pool[PS];
  float4* sK   = (float4*)(pool);                 // [LEN] k0..3 f32
  float4* sVa  = (float4*)(pool + (size_t)LEN*16);// [LEN] v0..3
  float4* sVb  = (float4*)(pool + (size_t)LEN*32);// [LEN] v4..7
  uint4*  sT   = (uint4*) (pool + (size_t)LEN*48);// [NJ] qe01,qe23,keR01,keR23 bf16pk
  float4* sVE0 = (float4*)(pool + (size_t)LEN*48 + (size_t)NJ*16); // [NJ] ve0..3 f32
  float4* sVE1 = (float4*)(pool + (size_t)LEN*48 + (size_t)NJ*32); // [NJ] ve4..7 f32

  size_t kvbase = ((size_t)n*8 + hd)*LEN;
  for (int i = t; i < LEN; i += T) {
    uint2 kk = kvK[kvbase + i];
    uint4 vv = kvV[kvbase + i];
    sK[i]  = make_float4(bflo(kk.x), bfhi(kk.x), bflo(kk.y), bfhi(kk.y));
    sVa[i] = make_float4(bflo(vv.x), bfhi(vv.x), bflo(vv.y), bfhi(vv.y));
    sVb[i] = make_float4(bflo(vv.z), bfhi(vv.z), bflo(vv.w), bfhi(vv.w));
  }
  for (int j = t; j < NJ; j += T) {
    sT[j] = rqk[j];
    uint4 ve = rve[j];
    sVE0[j] = make_float4(bflo(ve.x), bfhi(ve.x), bflo(ve.y), bfhi(ve.y));
    sVE1[j] = make_float4(bflo(ve.z), bfhi(ve.z), bflo(ve.w), bfhi(ve.w));
  }

  float A0,A1,A2,Bc;
  {
    int c0 = hd, c1 = 8+hd, c2 = 16+hd;
    float s0 = lbn[c0]*rsqrtf(lbn[72+c0]+EPSF);
    float s1 = lbn[c1]*rsqrtf(lbn[72+c1]+EPSF);
    float s2 = lbn[c2]*rsqrtf(lbn[72+c2]+EPSF);
    float t0 = fmaf(-lbn[48+c0], s0, lbn[24+c0]);
    float t1 = fmaf(-lbn[48+c1], s1, lbn[24+c1]);
    float t2 = fmaf(-lbn[48+c2], s2, lbn[24+c2]);
    A0 = s0*LOG2E; A1 = s1*LOG2E; A2 = s2*LOG2E; Bc = (t0+t1+t2)*LOG2E;
  }

  int g  = t / HALF;
  int tl = t % HALF;
  int y0 = g * YR;

  float q[2][4];
  #pragma unroll
  for (int i = 0; i < 2; ++i) {
    float4 qq = *(const float4*)(qb + (kvbase + tl + i*HALF)*4);
    q[i][0]=qq.x; q[i][1]=qq.y; q[i][2]=qq.z; q[i][3]=qq.w;
  }
  float m[2], ss[2], acc[2][8], lr[2][CH];
  #pragma unroll
  for (int i=0;i<2;++i){ m[i]=-3.0e38f; ss[i]=0.f;
    #pragma unroll
    for(int d=0;d<8;++d) acc[i][d]=0.f; }

  __syncthreads();

  for (int yc = 0; yc < YR; yc += CH) {
    // ---- pass A: logits into regs ----
    #pragma unroll
    for (int c = 0; c < CH; ++c) {
      int y = y0 + yc + c;
      float4 kk = sK[y];   // broadcast
      #pragma unroll
      for (int i = 0; i < 2; ++i) {
        int j = y - (tl + i*HALF) + (LEN-1);
        uint4 qe = sT[j];
        float qk = fmaf(q[i][3],kk.w, fmaf(q[i][2],kk.z, fmaf(q[i][1],kk.y, q[i][0]*kk.x)));
        float qr = fmaf(q[i][1],bfhiraw(qe.x), q[i][0]*bflo(qe.x));
        qr = fmaf(q[i][3],bfhiraw(qe.y), fmaf(q[i][2],bflo(qe.y), qr));
        float kr = fmaf(kk.y,bfhiraw(qe.z), kk.x*bflo(qe.z));
        kr = fmaf(kk.w,bfhiraw(qe.w), fmaf(kk.z,bflo(qe.w), kr));
        lr[i][c] = fmaf(qk,A0, fmaf(qr,A1, fmaf(kr,A2, Bc)));
      }
    }
    // ---- branchless chunk rescale ----
    #pragma unroll
    for (int i = 0; i < 2; ++i) {
      float cm = fmaxf(fmaxf(lr[i][0], lr[i][1]), fmaxf(lr[i][2], lr[i][3]));
      float mn = fmaxf(m[i], cm);
      float sc = __builtin_amdgcn_exp2f(m[i] - mn);
      m[i] = mn; ss[i] *= sc;
      #pragma unroll
      for (int d = 0; d < 8; ++d) acc[i][d] *= sc;
    }
    // ---- pass B: exp + accumulate ----
    #pragma unroll
    for (int c = 0; c < CH; ++c) {
      int y = y0 + yc + c;
      float4 va = sVa[y], vb = sVb[y];   // broadcast
      #pragma unroll
      for (int i = 0; i < 2; ++i) {
        int j = y - (tl + i*HALF) + (LEN-1);
        float4 ea = sVE0[j];
        float4 eb = sVE1[j];
        float e = __builtin_amdgcn_exp2f(lr[i][c] - m[i]);
        ss[i] += e;
        acc[i][0] = fmaf(e, va.x + ea.x, acc[i][0]);
        acc[i][1] = fmaf(e, va.y + ea.y, acc[i][1]);
        acc[i][2] = fmaf(e, va.z + ea.z, acc[i][2]);
        acc[i][3] = fmaf(e, va.w + ea.w, acc[i][3]);
        acc[i][4] = fmaf(e, vb.x + eb.x, acc[i][4]);
        acc[i][5] = fmaf(e, vb.y + eb.y, acc[i][5]);
        acc[i][6] = fmaf(e, vb.z + eb.z, acc[i][6]);
        acc[i][7] = fmaf(e, vb.w + eb.w, acc[i][7]);
      }
    }
  }

  // ---- G-way merge via LDS ----
  __syncthreads();
  float4* M0 = (float4*)(pool);                          // [(G-1)*LEN]
  float4* M1 = (float4*)(pool + (size_t)(G-1)*LEN*16);   // [(G-1)*LEN]
  float2* MS = (float2*)(pool + (size_t)(G-1)*LEN*32);   // [(G-1)*LEN]
  if (g > 0) {
    #pragma unroll
    for (int i = 0; i < 2; ++i) {
      int slot = ((g-1)*HALF + tl)*2 + i;
      M0[slot] = make_float4(acc[i][0],acc[i][1],acc[i][2],acc[i][3]);
      M1[slot] = make_float4(acc[i][4],acc[i][5],acc[i][6],acc[i][7]);
      MS[slot] = make_float2(m[i], ss[i]);
    }
  }
  __syncthreads();
  if (g == 0) {
    #pragma unroll
    for (int i = 0; i < 2; ++i) {
      float M = m[i];
      float2 oms[G-1];
      #pragma unroll
      for (int gg = 1; gg < G; ++gg) {
        oms[gg-1] = MS[((gg-1)*HALF + tl)*2 + i];
        M = fmaxf(M, oms[gg-1].x);
      }
      float w0 = __builtin_amdgcn_exp2f(m[i] - M);
      float st = ss[i]*w0;
      float a[8];
      #pragma unroll
      for (int d = 0; d < 8; ++d) a[d] = acc[i][d]*w0;
      #pragma unroll
      for (int gg = 1; gg < G; ++gg) {
        int slot = ((gg-1)*HALF + tl)*2 + i;
        float wg = __builtin_amdgcn_exp2f(oms[gg-1].x - M);
        st += oms[gg-1].y*wg;
        float4 a0 = M0[slot];
        float4 a1 = M1[slot];
        a[0] = fmaf(a0.x, wg, a[0]); a[1] = fmaf(a0.y, wg, a[1]);
        a[2] = fmaf(a0.z, wg, a[2]); a[3] = fmaf(a0.w, wg, a[3]);
        a[4] = fmaf(a1.x, wg, a[4]); a[5] = fmaf(a1.y, wg, a[5]);
        a[6] = fmaf(a1.z, wg, a[6]); a[7] = fmaf(a1.w, wg, a[7]);
      }
      float inv = 1.0f / st;
      int x = tl + i*HALF;
      float* dst = out + ((size_t)x*XS + (size_t)n*NS)*64 + hd*8;
      float4 lo, hi;
      lo.x = a[0]*inv; lo.y = a[1]*inv; lo.z = a[2]*inv; lo.w = a[3]*inv;
      hi.x = a[4]*inv; hi.y = a[5]*inv; hi.z = a[6]*inv; hi.w = a[7]*inv;
      if (RELUO) {
        lo.x=fmaxf(lo.x,0.f); lo.y=fmaxf(lo.y,0.f); lo.z=fmaxf(lo.z,0.f); lo.w=fmaxf(lo.w,0.f);
        hi.x=fmaxf(hi.x,0.f); hi.y=fmaxf(hi.y,0.f); hi.z=fmaxf(hi.z,0.f); hi.w=fmaxf(hi.w,0.f);
      }
      *(float4*)dst = lo;
      *((float4*)dst + 1) = hi;
    }
  }
}

// ---------------- conv3 + bn + residual + relu : NHWC in -> NCHW out ----------------
__global__ __launch_bounds__(256)
void k_conv3(const float* __restrict__ in, const float* __restrict__ w,
             const float* __restrict__ bn, const float* __restrict__ resid,
             float* __restrict__ out) {
  __shared__ float L[64*65];
  int tid = threadIdx.x;
  int p0 = blockIdx.x * 64;
  const float4* src = (const float4*)(in + (size_t)p0*64);
  #pragma unroll
  for (int k = 0; k < 4; ++k) {
    int f4 = tid + k*256;
    float4 v = src[f4];
    int f = f4*4; int p = f >> 6, o = f & 63;
    L[p*65+o] = v.x; L[p*65+o+1] = v.y; L[p*65+o+2] = v.z; L[p*65+o+3] = v.w;
  }
  __syncthreads();
  int lane = tid & 63;
  int wvs = __builtin_amdgcn_readfirstlane(tid >> 6);
  float xv[64];
  #pragma unroll
  for (int c = 0; c < 64; ++c) xv[c] = L[lane*65 + c];
  #pragma unroll
  for (int r = 0; r < 16; ++r) {
    int o = wvs*16 + r;
    const float* wr = w + o*64;               // scalar -> s_load
    float acc = 0.f;
    #pragma unroll
    for (int c = 0; c < 64; ++c) acc = fmaf(wr[c], xv[c], acc);
    float s = bn[o] * rsqrtf(bn[192+o] + EPSF);
    float val = fmaf(acc, s, fmaf(-bn[128+o], s, bn[64+o]));
    size_t idx = (size_t)o*32768 + p0 + lane;
    out[idx] = fmaxf(val + resid[idx], 0.f);
  }
}

extern "C" void kernel_launch(void* const* d_in, const int* in_sizes, int n_in,
                              void* d_out, int out_size, void* d_ws, size_t ws_size,
                              hipStream_t stream) {
  const float* x         = (const float*)d_in[0];
  const float* conv1_w   = (const float*)d_in[1];
  const float* bn1       = (const float*)d_in[2];
  const float* kqv_w_h   = (const float*)d_in[3];
  const float* kqv_bn_h  = (const float*)d_in[4];
  const float* lbn_h     = (const float*)d_in[5];
  const float* rel_h     = (const float*)d_in[6];
  const float* kqv_w_w   = (const float*)d_in[7];
  const float* kqv_bn_w  = (const float*)d_in[8];
  const float* lbn_w     = (const float*)d_in[9];
  const float* rel_w     = (const float*)d_in[10];
  const float* conv3_w   = (const float*)d_in[11];
  const float* bn3       = (const float*)d_in[12];
  float* outp = (float*)d_out;
  char* ws = (char*)d_ws;

  float* A    = (float*)(ws);                    // 8 MiB
  uint4* kvV  = (uint4*)(ws + 8388608);          // 4 MiB
  uint2* kvK  = (uint2*)(ws + 12582912);         // 2 MiB
  float* qb   = (float*)(ws + 14680064);         // 4 MiB (f32 q)
  uint4* rqkH = (uint4*)(ws + 18874368);
  uint4* rveH = (uint4*)(ws + 18882560);
  uint4* rqkW = (uint4*)(ws + 18890752);
  uint4* rveW = (uint4*)(ws + 18894848);

  k_relpack<<<2, 512, 0, stream>>>(rel_h, rel_w, rqkH, rveH, rqkW, rveW);

  // conv1 + bn1 + relu : x NCHW -> A NHWC
  k_conv1<<<512, 256, 0, stream>>>(x, conv1_w, bn1, A);

  // axial-H: n = w (128), seq = h (256); G=4 -> 512 thr
  k_kqv<256,128,1><<<dim3(128,4), 512, 0, stream>>>(A, kqv_w_h, kqv_bn_h, kvV, kvK, qb);
  k_attn2<256,4,false,128,1><<<1024, 512, 0, stream>>>(kvV, kvK, qb, rqkH, rveH, lbn_h, A);

  // axial-W: n = h (256), seq = w (128); G=4 -> 256 thr; relu fused
  k_kqv<128,1,128><<<dim3(256,2), 512, 0, stream>>>(A, kqv_w_w, kqv_bn_w, kvV, kvK, qb);
  k_attn2<128,4,true,1,128><<<2048, 256, 0, stream>>>(kvV, kvK, qb, rqkW, rveW, lbn_w, A);

  // conv3 + bn3 + residual + relu : A NHWC -> out NCHW
  k_conv3<<<512, 256, 0, stream>>>(A, conv3_w, bn3, x, outp);
}

// Round 6
// 186.991 us; speedup vs baseline: 1.3450x; 1.0153x over previous
//
#include <hip/hip_runtime.h>
#include <stdint.h>

#define EPSF 1e-5f
#define LOG2E 1.4426950408889634f

typedef float f32x2 __attribute__((ext_vector_type(2)));
typedef float f32x4 __attribute__((ext_vector_type(4)));

__device__ __forceinline__ float bflo(uint32_t u){ union{uint32_t u;float f;}c; c.u=u<<16; return c.f; }
__device__ __forceinline__ float bfhi(uint32_t u){ union{uint32_t u;float f;}c; c.u=u&0xffff0000u; return c.f; }
// raw high-half: value == bf16_hi * (1+delta), |delta| <= 2^-7
__device__ __forceinline__ float bfhiraw(uint32_t u){ union{uint32_t u;float f;}c; c.u=u; return c.f; }
__device__ __forceinline__ uint32_t f2bf(float f){ union{float f;uint32_t u;}c; c.f=f; uint32_t u=c.u; return (u + 0x7fffu + ((u>>16)&1u)) >> 16; }
__device__ __forceinline__ uint32_t pk2(float a, float b){ return f2bf(a) | (f2bf(b)<<16); }

// ---------------- rel_enc packing (both tables, one launch, bf16) ----------------
__global__ void k_relpack(const float* __restrict__ relH, const float* __restrict__ relW,
                          uint4* __restrict__ rqkH, uint4* __restrict__ rveH,
                          uint4* __restrict__ rqkW, uint4* __restrict__ rveW) {
  int NJ = blockIdx.x ? 255 : 511;
  const float* rel = blockIdx.x ? relW : relH;
  uint4* rqk = blockIdx.x ? rqkW : rqkH;
  uint4* rve = blockIdx.x ? rveW : rveH;
  int j = threadIdx.x;
  if (j >= NJ) return;
  const float* q = rel;
  const float* k = rel + 4*NJ;
  const float* v = rel + 8*NJ;
  int jr = NJ-1-j;
  uint4 a;
  a.x = pk2(q[0*NJ+j], q[1*NJ+j]);
  a.y = pk2(q[2*NJ+j], q[3*NJ+j]);
  a.z = pk2(k[0*NJ+jr], k[1*NJ+jr]);
  a.w = pk2(k[2*NJ+jr], k[3*NJ+jr]);
  rqk[j] = a;
  uint4 b;
  b.x = pk2(v[0*NJ+j], v[1*NJ+j]);
  b.y = pk2(v[2*NJ+j], v[3*NJ+j]);
  b.z = pk2(v[4*NJ+j], v[5*NJ+j]);
  b.w = pk2(v[6*NJ+j], v[7*NJ+j]);
  rve[j] = b;
}

// ---------------- conv1 + bn + relu : NCHW in -> NHWC out ----------------
__global__ __launch_bounds__(256)
void k_conv1(const float* __restrict__ in, const float* __restrict__ w,
             const float* __restrict__ bn, float* __restrict__ out) {
  __shared__ float L[64*65];
  int tid = threadIdx.x;
  int p0 = blockIdx.x * 64;
  int lane = tid & 63;
  int wvs = __builtin_amdgcn_readfirstlane(tid >> 6);   // wave-uniform -> SGPR
  // stage NCHW tile transposed: L[p][c], coalesced dword loads (lane = p)
  #pragma unroll
  for (int rr = 0; rr < 16; ++rr) {
    int c = wvs*16 + rr;
    L[lane*65 + c] = in[(size_t)c*32768 + p0 + lane];
  }
  __syncthreads();
  f32x2 xv2[32];
  #pragma unroll
  for (int c2 = 0; c2 < 32; ++c2) {
    xv2[c2].x = L[lane*65 + 2*c2];
    xv2[c2].y = L[lane*65 + 2*c2 + 1];
  }
  float val[16];
  #pragma unroll
  for (int r = 0; r < 16; ++r) {
    int o = wvs*16 + r;                       // scalar -> s_load weights
    const f32x2* wr = (const f32x2*)(w + o*64);
    f32x2 a2 = {0.f, 0.f};
    #pragma unroll
    for (int c2 = 0; c2 < 32; ++c2) a2 = wr[c2]*xv2[c2] + a2;   // v_pk_fma_f32
    float acc = a2.x + a2.y;
    float s = bn[o] * rsqrtf(bn[192+o] + EPSF);
    val[r] = fmaxf(fmaf(acc, s, fmaf(-bn[128+o], s, bn[64+o])), 0.f);
  }
  __syncthreads();
  #pragma unroll
  for (int r = 0; r < 16; ++r) L[lane*65 + wvs*16 + r] = val[r];
  __syncthreads();
  float4* dst = (float4*)(out + (size_t)p0*64);
  #pragma unroll
  for (int k = 0; k < 4; ++k) {
    int f4 = tid + k*256;
    int f = f4*4; int p = f >> 6, o = f & 63;
    float4 v;
    v.x = L[p*65+o]; v.y = L[p*65+o+1]; v.z = L[p*65+o+2]; v.w = L[p*65+o+3];
    dst[f4] = v;
  }
}

// ---------------- kqv projection + bn -> bf16 K/V + f32 Q ----------------
template<int LEN, int RS, int CS>
__global__ __launch_bounds__(512)
void k_kqv(const float* __restrict__ in, const float* __restrict__ w,
           const float* __restrict__ bn, uint4* __restrict__ kvV,
           uint2* __restrict__ kvK, float* __restrict__ qb) {
  __shared__ float L[64*65];
  int tid = threadIdx.x;
  int n = blockIdx.x;
  int y0 = blockIdx.y * 64;
  #pragma unroll
  for (int rr = 0; rr < 8; ++rr) {
    int idx = tid + rr*512;
    int yy = idx >> 6, c = idx & 63;
    L[yy*65 + c] = in[((size_t)(y0+yy)*RS + (size_t)n*CS)*64 + c];
  }
  __syncthreads();
  int hd = __builtin_amdgcn_readfirstlane(tid >> 6);   // scalar head index
  int yy = tid & 63;
  f32x2 xv2[32];
  #pragma unroll
  for (int c2 = 0; c2 < 32; ++c2) {
    xv2[c2].x = L[yy*65 + 2*c2];
    xv2[c2].y = L[yy*65 + 2*c2 + 1];
  }
  float val[16];
  #pragma unroll
  for (int r = 0; r < 16; ++r) {
    int o = hd*16 + r;
    const f32x2* wr = (const f32x2*)(w + o*64);        // scalar -> s_load
    f32x2 a2 = {0.f, 0.f};
    #pragma unroll
    for (int c2 = 0; c2 < 32; ++c2) a2 = wr[c2]*xv2[c2] + a2;
    float acc = a2.x + a2.y;
    float s = bn[o] * rsqrtf(bn[384+o] + EPSF);
    val[r] = fmaf(acc, s, fmaf(-bn[256+o], s, bn[128+o]));
  }
  size_t base = ((size_t)n*8 + hd)*LEN + (y0 + yy);
  kvK[base] = make_uint2(pk2(val[0],val[1]), pk2(val[2],val[3]));
  kvV[base] = make_uint4(pk2(val[8],val[9]),  pk2(val[10],val[11]),
                         pk2(val[12],val[13]), pk2(val[14],val[15]));
  float4 qq; qq.x = val[4]; qq.y = val[5]; qq.z = val[6]; qq.w = val[7];
  *(float4*)(qb + base*4) = qq;
}

// ---------------- axial attention core (v6: packed-f32, prescaled tables) ----------------
// logit(x,y) = q . (A0L*k + A1L*qe[j]) + k . (A2L*keR[j])    (Bc dropped: softmax-invariant)
// Tables staged per block with scales folded in. G y-groups of HALF lanes, CH=4.
template<int LEN, int G, bool RELUO, int XS, int NS>
__global__ __launch_bounds__(LEN*G/2, 2)
void k_attn2(const uint4* __restrict__ kvV, const uint2* __restrict__ kvK,
             const float* __restrict__ qb, const uint4* __restrict__ rqk,
             const uint4* __restrict__ rve, const float* __restrict__ lbn,
             float* __restrict__ out) {
  constexpr int NJ = 2*LEN-1;
  constexpr int HALF = LEN/2;
  constexpr int T = LEN*G/2;
  constexpr int YR = LEN/G;
  constexpr int CH = 4;
  constexpr size_t S1 = (size_t)LEN*64 + (size_t)NJ*48;   // staging
  constexpr size_t S2 = (size_t)(G-1)*LEN*40;             // merge
  constexpr size_t PS = S1 > S2 ? S1 : S2;
  int n  = blockIdx.x >> 3;
  int hd = blockIdx.x & 7;
  int t  = threadIdx.x;

  __shared__ __align__(16) char pool[PS];
  f32x4* sKt = (f32x4*)(pool);                              // [LEN] A0L*k
  f32x4* sKr = (f32x4*)(pool + (size_t)LEN*16);             // [LEN] raw k
  f32x4* sVa = (f32x4*)(pool + (size_t)LEN*32);             // [LEN] v0..3
  f32x4* sVb = (f32x4*)(pool + (size_t)LEN*48);             // [LEN] v4..7
  f32x4* sQE = (f32x4*)(pool + (size_t)LEN*64);             // [NJ] A1L*qe
  f32x4* sKE = (f32x4*)(pool + (size_t)LEN*64 + (size_t)NJ*16); // [NJ] A2L*keR
  uint4* sVE = (uint4*)(pool + (size_t)LEN*64 + (size_t)NJ*32); // [NJ] ve bf16pk

  // logits-bn scales (block-uniform; bias dropped — softmax-invariant)
  float A0L, A1L, A2L;
  {
    int c0 = hd, c1 = 8+hd, c2 = 16+hd;
    A0L = lbn[c0]*rsqrtf(lbn[72+c0]+EPSF)*LOG2E;
    A1L = lbn[c1]*rsqrtf(lbn[72+c1]+EPSF)*LOG2E;
    A2L = lbn[c2]*rsqrtf(lbn[72+c2]+EPSF)*LOG2E;
  }

  size_t kvbase = ((size_t)n*8 + hd)*LEN;
  for (int i = t; i < LEN; i += T) {
    uint2 kk = kvK[kvbase + i];
    uint4 vv = kvV[kvbase + i];
    float k0=bflo(kk.x), k1=bfhi(kk.x), k2=bflo(kk.y), k3=bfhi(kk.y);
    f32x4 kt; kt.x=k0*A0L; kt.y=k1*A0L; kt.z=k2*A0L; kt.w=k3*A0L;
    sKt[i] = kt;
    f32x4 kr; kr.x=k0; kr.y=k1; kr.z=k2; kr.w=k3;
    sKr[i] = kr;
    f32x4 va; va.x=bflo(vv.x); va.y=bfhi(vv.x); va.z=bflo(vv.y); va.w=bfhi(vv.y);
    sVa[i] = va;
    f32x4 vb; vb.x=bflo(vv.z); vb.y=bfhi(vv.z); vb.z=bflo(vv.w); vb.w=bfhi(vv.w);
    sVb[i] = vb;
  }
  for (int j = t; j < NJ; j += T) {
    uint4 a = rqk[j];
    f32x4 qe; qe.x=bflo(a.x)*A1L; qe.y=bfhi(a.x)*A1L; qe.z=bflo(a.y)*A1L; qe.w=bfhi(a.y)*A1L;
    sQE[j] = qe;
    f32x4 ke; ke.x=bflo(a.z)*A2L; ke.y=bfhi(a.z)*A2L; ke.z=bflo(a.w)*A2L; ke.w=bfhi(a.w)*A2L;
    sKE[j] = ke;
    sVE[j] = rve[j];
  }

  int g  = t / HALF;
  int tl = t % HALF;
  int y0 = g * YR;

  f32x4 qv[2];
  qv[0] = *(const f32x4*)(qb + (kvbase + tl)*4);
  qv[1] = *(const f32x4*)(qb + (kvbase + tl + HALF)*4);

  float m[2], ss[2], lr[2][CH];
  f32x2 acc2[2][4];
  #pragma unroll
  for (int i=0;i<2;++i){ m[i]=-3.0e38f; ss[i]=0.f;
    #pragma unroll
    for(int d=0;d<4;++d){ acc2[i][d].x=0.f; acc2[i][d].y=0.f; } }

  __syncthreads();

  for (int yc = 0; yc < YR; yc += CH) {
    // ---- pass A: logits (packed f32) ----
    #pragma unroll
    for (int c = 0; c < CH; ++c) {
      int y = y0 + yc + c;
      f32x4 kt = sKt[y];     // uniform -> broadcast
      f32x4 kr = sKr[y];
      #pragma unroll
      for (int i = 0; i < 2; ++i) {
        int j = y - (tl + i*HALF) + (LEN-1);
        f32x4 qe = sQE[j];
        f32x4 ke = sKE[j];
        f32x2 t0 = kt.lo + qe.lo;          // v_pk_add_f32
        f32x2 t1 = kt.hi + qe.hi;
        f32x2 s = qv[i].lo*t0 + qv[i].hi*t1;   // pk_mul + pk_fma
        s = kr.lo*ke.lo + s;               // pk_fma
        s = kr.hi*ke.hi + s;               // pk_fma
        lr[i][c] = s.x + s.y;
      }
    }
    // ---- branchless chunk rescale ----
    #pragma unroll
    for (int i = 0; i < 2; ++i) {
      float cm = fmaxf(fmaxf(lr[i][0], lr[i][1]), fmaxf(lr[i][2], lr[i][3]));
      float mn = fmaxf(m[i], cm);
      float sc = __builtin_amdgcn_exp2f(m[i] - mn);
      m[i] = mn; ss[i] *= sc;
      f32x2 sc2 = {sc, sc};
      #pragma unroll
      for (int d = 0; d < 4; ++d) acc2[i][d] *= sc2;
    }
    // ---- pass B: exp + packed accumulate ----
    #pragma unroll
    for (int c = 0; c < CH; ++c) {
      int y = y0 + yc + c;
      f32x4 va = sVa[y], vb = sVb[y];   // uniform -> broadcast
      #pragma unroll
      for (int i = 0; i < 2; ++i) {
        int j = y - (tl + i*HALF) + (LEN-1);
        uint4 ve = sVE[j];
        float e = __builtin_amdgcn_exp2f(lr[i][c] - m[i]);
        ss[i] += e;
        f32x2 e2 = {e, e};
        f32x2 w0; w0.x = bflo(ve.x); w0.y = bfhiraw(ve.x); w0 = va.lo + w0;
        f32x2 w1; w1.x = bflo(ve.y); w1.y = bfhiraw(ve.y); w1 = va.hi + w1;
        f32x2 w2; w2.x = bflo(ve.z); w2.y = bfhiraw(ve.z); w2 = vb.lo + w2;
        f32x2 w3; w3.x = bflo(ve.w); w3.y = bfhiraw(ve.w); w3 = vb.hi + w3;
        acc2[i][0] = e2*w0 + acc2[i][0];
        acc2[i][1] = e2*w1 + acc2[i][1];
        acc2[i][2] = e2*w2 + acc2[i][2];
        acc2[i][3] = e2*w3 + acc2[i][3];
      }
    }
  }

  // ---- G-way merge via LDS ----
  __syncthreads();
  float4* M0 = (float4*)(pool);                          // [(G-1)*LEN]
  float4* M1 = (float4*)(pool + (size_t)(G-1)*LEN*16);   // [(G-1)*LEN]
  float2* MS = (float2*)(pool + (size_t)(G-1)*LEN*32);   // [(G-1)*LEN]
  if (g > 0) {
    #pragma unroll
    for (int i = 0; i < 2; ++i) {
      int slot = ((g-1)*HALF + tl)*2 + i;
      M0[slot] = make_float4(acc2[i][0].x,acc2[i][0].y,acc2[i][1].x,acc2[i][1].y);
      M1[slot] = make_float4(acc2[i][2].x,acc2[i][2].y,acc2[i][3].x,acc2[i][3].y);
      MS[slot] = make_float2(m[i], ss[i]);
    }
  }
  __syncthreads();
  if (g == 0) {
    #pragma unroll
    for (int i = 0; i < 2; ++i) {
      float M = m[i];
      float2 oms[G-1];
      #pragma unroll
      for (int gg = 1; gg < G; ++gg) {
        oms[gg-1] = MS[((gg-1)*HALF + tl)*2 + i];
        M = fmaxf(M, oms[gg-1].x);
      }
      float w0 = __builtin_amdgcn_exp2f(m[i] - M);
      float st = ss[i]*w0;
      float a[8];
      a[0]=acc2[i][0].x*w0; a[1]=acc2[i][0].y*w0; a[2]=acc2[i][1].x*w0; a[3]=acc2[i][1].y*w0;
      a[4]=acc2[i][2].x*w0; a[5]=acc2[i][2].y*w0; a[6]=acc2[i][3].x*w0; a[7]=acc2[i][3].y*w0;
      #pragma unroll
      for (int gg = 1; gg < G; ++gg) {
        int slot = ((gg-1)*HALF + tl)*2 + i;
        float wg = __builtin_amdgcn_exp2f(oms[gg-1].x - M);
        st += oms[gg-1].y*wg;
        float4 a0 = M0[slot];
        float4 a1 = M1[slot];
        a[0] = fmaf(a0.x, wg, a[0]); a[1] = fmaf(a0.y, wg, a[1]);
        a[2] = fmaf(a0.z, wg, a[2]); a[3] = fmaf(a0.w, wg, a[3]);
        a[4] = fmaf(a1.x, wg, a[4]); a[5] = fmaf(a1.y, wg, a[5]);
        a[6] = fmaf(a1.z, wg, a[6]); a[7] = fmaf(a1.w, wg, a[7]);
      }
      float inv = 1.0f / st;
      int x = tl + i*HALF;
      float* dst = out + ((size_t)x*XS + (size_t)n*NS)*64 + hd*8;
      float4 lo, hi;
      lo.x = a[0]*inv; lo.y = a[1]*inv; lo.z = a[2]*inv; lo.w = a[3]*inv;
      hi.x = a[4]*inv; hi.y = a[5]*inv; hi.z = a[6]*inv; hi.w = a[7]*inv;
      if (RELUO) {
        lo.x=fmaxf(lo.x,0.f); lo.y=fmaxf(lo.y,0.f); lo.z=fmaxf(lo.z,0.f); lo.w=fmaxf(lo.w,0.f);
        hi.x=fmaxf(hi.x,0.f); hi.y=fmaxf(hi.y,0.f); hi.z=fmaxf(hi.z,0.f); hi.w=fmaxf(hi.w,0.f);
      }
      *(float4*)dst = lo;
      *((float4*)dst + 1) = hi;
    }
  }
}

// ---------------- conv3 + bn + residual + relu : NHWC in -> NCHW out ----------------
__global__ __launch_bounds__(256)
void k_conv3(const float* __restrict__ in, const float* __restrict__ w,
             const float* __restrict__ bn, const float* __restrict__ resid,
             float* __restrict__ out) {
  __shared__ float L[64*65];
  int tid = threadIdx.x;
  int p0 = blockIdx.x * 64;
  const float4* src = (const float4*)(in + (size_t)p0*64);
  #pragma unroll
  for (int k = 0; k < 4; ++k) {
    int f4 = tid + k*256;
    float4 v = src[f4];
    int f = f4*4; int p = f >> 6, o = f & 63;
    L[p*65+o] = v.x; L[p*65+o+1] = v.y; L[p*65+o+2] = v.z; L[p*65+o+3] = v.w;
  }
  __syncthreads();
  int lane = tid & 63;
  int wvs = __builtin_amdgcn_readfirstlane(tid >> 6);
  f32x2 xv2[32];
  #pragma unroll
  for (int c2 = 0; c2 < 32; ++c2) {
    xv2[c2].x = L[lane*65 + 2*c2];
    xv2[c2].y = L[lane*65 + 2*c2 + 1];
  }
  #pragma unroll
  for (int r = 0; r < 16; ++r) {
    int o = wvs*16 + r;
    const f32x2* wr = (const f32x2*)(w + o*64);        // scalar -> s_load
    f32x2 a2 = {0.f, 0.f};
    #pragma unroll
    for (int c2 = 0; c2 < 32; ++c2) a2 = wr[c2]*xv2[c2] + a2;
    float acc = a2.x + a2.y;
    float s = bn[o] * rsqrtf(bn[192+o] + EPSF);
    float val = fmaf(acc, s, fmaf(-bn[128+o], s, bn[64+o]));
    size_t idx = (size_t)o*32768 + p0 + lane;
    out[idx] = fmaxf(val + resid[idx], 0.f);
  }
}

extern "C" void kernel_launch(void* const* d_in, const int* in_sizes, int n_in,
                              void* d_out, int out_size, void* d_ws, size_t ws_size,
                              hipStream_t stream) {
  const float* x         = (const float*)d_in[0];
  const float* conv1_w   = (const float*)d_in[1];
  const float* bn1       = (const float*)d_in[2];
  const float* kqv_w_h   = (const float*)d_in[3];
  const float* kqv_bn_h  = (const float*)d_in[4];
  const float* lbn_h     = (const float*)d_in[5];
  const float* rel_h     = (const float*)d_in[6];
  const float* kqv_w_w   = (const float*)d_in[7];
  const float* kqv_bn_w  = (const float*)d_in[8];
  const float* lbn_w     = (const float*)d_in[9];
  const float* rel_w     = (const float*)d_in[10];
  const float* conv3_w   = (const float*)d_in[11];
  const float* bn3       = (const float*)d_in[12];
  float* outp = (float*)d_out;
  char* ws = (char*)d_ws;

  float* A    = (float*)(ws);                    // 8 MiB
  uint4* kvV  = (uint4*)(ws + 8388608);          // 4 MiB
  uint2* kvK  = (uint2*)(ws + 12582912);         // 2 MiB
  float* qb   = (float*)(ws + 14680064);         // 4 MiB (f32 q)
  uint4* rqkH = (uint4*)(ws + 18874368);
  uint4* rveH = (uint4*)(ws + 18882560);
  uint4* rqkW = (uint4*)(ws + 18890752);
  uint4* rveW = (uint4*)(ws + 18894848);

  k_relpack<<<2, 512, 0, stream>>>(rel_h, rel_w, rqkH, rveH, rqkW, rveW);

  // conv1 + bn1 + relu : x NCHW -> A NHWC
  k_conv1<<<512, 256, 0, stream>>>(x, conv1_w, bn1, A);

  // axial-H: n = w (128), seq = h (256); G=4 -> 512 thr
  k_kqv<256,128,1><<<dim3(128,4), 512, 0, stream>>>(A, kqv_w_h, kqv_bn_h, kvV, kvK, qb);
  k_attn2<256,4,false,128,1><<<1024, 512, 0, stream>>>(kvV, kvK, qb, rqkH, rveH, lbn_h, A);

  // axial-W: n = h (256), seq = w (128); G=4 -> 256 thr; relu fused
  k_kqv<128,1,128><<<dim3(256,2), 512, 0, stream>>>(A, kqv_w_w, kqv_bn_w, kvV, kvK, qb);
  k_attn2<128,4,true,1,128><<<2048, 256, 0, stream>>>(kvV, kvK, qb, rqkW, rveW, lbn_w, A);

  // conv3 + bn3 + residual + relu : A NHWC -> out NCHW
  k_conv3<<<512, 256, 0, stream>>>(A, conv3_w, bn3, x, outp);
}

// Round 7
// 177.692 us; speedup vs baseline: 1.4154x; 1.0523x over previous
//
#include <hip/hip_runtime.h>
#include <stdint.h>

#define EPSF 1e-5f
#define LOG2E 1.4426950408889634f

typedef float f32x2 __attribute__((ext_vector_type(2)));
typedef float f32x4 __attribute__((ext_vector_type(4)));

__device__ __forceinline__ float bflo(uint32_t u){ union{uint32_t u;float f;}c; c.u=u<<16; return c.f; }
__device__ __forceinline__ float bfhi(uint32_t u){ union{uint32_t u;float f;}c; c.u=u&0xffff0000u; return c.f; }
// raw high-half: value == bf16_hi * (1+delta), |delta| <= 2^-7
__device__ __forceinline__ float bfhiraw(uint32_t u){ union{uint32_t u;float f;}c; c.u=u; return c.f; }
__device__ __forceinline__ uint32_t f2bf(float f){ union{float f;uint32_t u;}c; c.f=f; uint32_t u=c.u; return (u + 0x7fffu + ((u>>16)&1u)) >> 16; }
__device__ __forceinline__ uint32_t pk2(float a, float b){ return f2bf(a) | (f2bf(b)<<16); }

// ---------------- rel_enc packing (both tables, one launch, bf16) ----------------
__global__ void k_relpack(const float* __restrict__ relH, const float* __restrict__ relW,
                          uint4* __restrict__ rqkH, uint4* __restrict__ rveH,
                          uint4* __restrict__ rqkW, uint4* __restrict__ rveW) {
  int NJ = blockIdx.x ? 255 : 511;
  const float* rel = blockIdx.x ? relW : relH;
  uint4* rqk = blockIdx.x ? rqkW : rqkH;
  uint4* rve = blockIdx.x ? rveW : rveH;
  int j = threadIdx.x;
  if (j >= NJ) return;
  const float* q = rel;
  const float* k = rel + 4*NJ;
  const float* v = rel + 8*NJ;
  int jr = NJ-1-j;
  uint4 a;
  a.x = pk2(q[0*NJ+j], q[1*NJ+j]);
  a.y = pk2(q[2*NJ+j], q[3*NJ+j]);
  a.z = pk2(k[0*NJ+jr], k[1*NJ+jr]);
  a.w = pk2(k[2*NJ+jr], k[3*NJ+jr]);
  rqk[j] = a;
  uint4 b;
  b.x = pk2(v[0*NJ+j], v[1*NJ+j]);
  b.y = pk2(v[2*NJ+j], v[3*NJ+j]);
  b.z = pk2(v[4*NJ+j], v[5*NJ+j]);
  b.w = pk2(v[6*NJ+j], v[7*NJ+j]);
  rve[j] = b;
}

// ---------------- conv1 + bn + relu : NCHW in -> NHWC out ----------------
__global__ __launch_bounds__(256)
void k_conv1(const float* __restrict__ in, const float* __restrict__ w,
             const float* __restrict__ bn, float* __restrict__ out) {
  __shared__ float L[64*65];
  int tid = threadIdx.x;
  int p0 = blockIdx.x * 64;
  int lane = tid & 63;
  int wvs = __builtin_amdgcn_readfirstlane(tid >> 6);
  #pragma unroll
  for (int rr = 0; rr < 16; ++rr) {
    int c = wvs*16 + rr;
    L[lane*65 + c] = in[(size_t)c*32768 + p0 + lane];
  }
  __syncthreads();
  f32x2 xv2[32];
  #pragma unroll
  for (int c2 = 0; c2 < 32; ++c2) {
    xv2[c2].x = L[lane*65 + 2*c2];
    xv2[c2].y = L[lane*65 + 2*c2 + 1];
  }
  float val[16];
  #pragma unroll
  for (int r = 0; r < 16; ++r) {
    int o = wvs*16 + r;
    const f32x2* wr = (const f32x2*)(w + o*64);
    f32x2 a2 = {0.f, 0.f};
    #pragma unroll
    for (int c2 = 0; c2 < 32; ++c2) a2 = wr[c2]*xv2[c2] + a2;
    float acc = a2.x + a2.y;
    float s = bn[o] * rsqrtf(bn[192+o] + EPSF);
    val[r] = fmaxf(fmaf(acc, s, fmaf(-bn[128+o], s, bn[64+o])), 0.f);
  }
  __syncthreads();
  #pragma unroll
  for (int r = 0; r < 16; ++r) L[lane*65 + wvs*16 + r] = val[r];
  __syncthreads();
  float4* dst = (float4*)(out + (size_t)p0*64);
  #pragma unroll
  for (int k = 0; k < 4; ++k) {
    int f4 = tid + k*256;
    int f = f4*4; int p = f >> 6, o = f & 63;
    float4 v;
    v.x = L[p*65+o]; v.y = L[p*65+o+1]; v.z = L[p*65+o+2]; v.w = L[p*65+o+3];
    dst[f4] = v;
  }
}

// ---------------- kqv projection + bn -> bf16 K/V + f32 Q ----------------
template<int LEN, int RS, int CS>
__global__ __launch_bounds__(512)
void k_kqv(const float* __restrict__ in, const float* __restrict__ w,
           const float* __restrict__ bn, uint4* __restrict__ kvV,
           uint2* __restrict__ kvK, float* __restrict__ qb) {
  __shared__ float L[64*65];
  int tid = threadIdx.x;
  int n = blockIdx.x;
  int y0 = blockIdx.y * 64;
  #pragma unroll
  for (int rr = 0; rr < 8; ++rr) {
    int idx = tid + rr*512;
    int yy = idx >> 6, c = idx & 63;
    L[yy*65 + c] = in[((size_t)(y0+yy)*RS + (size_t)n*CS)*64 + c];
  }
  __syncthreads();
  int hd = __builtin_amdgcn_readfirstlane(tid >> 6);
  int yy = tid & 63;
  f32x2 xv2[32];
  #pragma unroll
  for (int c2 = 0; c2 < 32; ++c2) {
    xv2[c2].x = L[yy*65 + 2*c2];
    xv2[c2].y = L[yy*65 + 2*c2 + 1];
  }
  float val[16];
  #pragma unroll
  for (int r = 0; r < 16; ++r) {
    int o = hd*16 + r;
    const f32x2* wr = (const f32x2*)(w + o*64);
    f32x2 a2 = {0.f, 0.f};
    #pragma unroll
    for (int c2 = 0; c2 < 32; ++c2) a2 = wr[c2]*xv2[c2] + a2;
    float acc = a2.x + a2.y;
    float s = bn[o] * rsqrtf(bn[384+o] + EPSF);
    val[r] = fmaf(acc, s, fmaf(-bn[256+o], s, bn[128+o]));
  }
  size_t base = ((size_t)n*8 + hd)*LEN + (y0 + yy);
  kvK[base] = make_uint2(pk2(val[0],val[1]), pk2(val[2],val[3]));
  kvV[base] = make_uint4(pk2(val[8],val[9]),  pk2(val[10],val[11]),
                         pk2(val[12],val[13]), pk2(val[14],val[15]));
  float4 qq; qq.x = val[4]; qq.y = val[5]; qq.z = val[6]; qq.w = val[7];
  *(float4*)(qb + base*4) = qq;
}

// ---------------- axial attention core (v7: XB=4 sliding window + parity LDS) ----------------
// thread owns x = 4*tl .. 4*tl+3; logit2 = kt.(q+ke'') + q.qe'
// kt = A0L*k (f32, bcast); qe' = A1L*qe, ke'' = (A2L/A0L)*keR (bf16, parity arrays)
struct Acc { f32x2 a[4]; };

__device__ __forceinline__ float pairA(f32x4 qv, uint4 e, f32x4 kt) {
  f32x2 qe0; qe0.x = bflo(e.x); qe0.y = bfhiraw(e.x);
  f32x2 qe1; qe1.x = bflo(e.y); qe1.y = bfhiraw(e.y);
  f32x2 ke0; ke0.x = bflo(e.z); ke0.y = bfhiraw(e.z);
  f32x2 ke1; ke1.x = bflo(e.w); ke1.y = bfhiraw(e.w);
  f32x2 t0 = qv.lo + ke0;
  f32x2 t1 = qv.hi + ke1;
  f32x2 s = t0*kt.lo;
  s = t1*kt.hi + s;
  s = qv.lo*qe0 + s;
  s = qv.hi*qe1 + s;
  return s.x + s.y;
}

__device__ __forceinline__ void pairB(float ex, uint4 e, f32x4 va, f32x4 vb,
                                      Acc& A, float& ss) {
  ss += ex;
  f32x2 e2; e2.x = ex; e2.y = ex;
  f32x2 w;
  w.x = bflo(e.x); w.y = bfhiraw(e.x); w = va.lo + w; A.a[0] = e2*w + A.a[0];
  w.x = bflo(e.y); w.y = bfhiraw(e.y); w = va.hi + w; A.a[1] = e2*w + A.a[1];
  w.x = bflo(e.z); w.y = bfhiraw(e.z); w = vb.lo + w; A.a[2] = e2*w + A.a[2];
  w.x = bflo(e.w); w.y = bfhiraw(e.w); w = vb.hi + w; A.a[3] = e2*w + A.a[3];
}

template<int LEN, int G, bool RELUO, int XS, int NS>
__global__ __launch_bounds__(LEN/4*G, 2)
void k_attn4(const uint4* __restrict__ kvV, const uint2* __restrict__ kvK,
             const float* __restrict__ qb, const uint4* __restrict__ rqk,
             const uint4* __restrict__ rve, const float* __restrict__ lbn,
             float* __restrict__ out) {
  constexpr int NJ = 2*LEN-1;
  constexpr int NJ4 = (NJ+1)/4;           // entries per parity array
  constexpr int XT = LEN/4;               // threads per y-group
  constexpr int T = XT*G;
  constexpr int YR = LEN/G;
  constexpr size_t S1 = (size_t)LEN*48 + (size_t)NJ4*4*16*2;
  constexpr size_t S2 = (size_t)(G-1)*LEN*40;
  constexpr size_t PS = S1 > S2 ? S1 : S2;
  int n  = blockIdx.x >> 3;
  int hd = blockIdx.x & 7;
  int t  = threadIdx.x;

  __shared__ __align__(16) char pool[PS];
  f32x4* sKt = (f32x4*)(pool);                              // [LEN]
  f32x4* sVa = (f32x4*)(pool + (size_t)LEN*16);             // [LEN]
  f32x4* sVb = (f32x4*)(pool + (size_t)LEN*32);             // [LEN]
  uint4* tQK = (uint4*)(pool + (size_t)LEN*48);             // [4][NJ4]
  uint4* tVE = (uint4*)(pool + (size_t)LEN*48 + (size_t)NJ4*64); // [4][NJ4]

  float A0L, A1L, A2L;
  {
    int c0 = hd, c1 = 8+hd, c2 = 16+hd;
    A0L = lbn[c0]*rsqrtf(lbn[72+c0]+EPSF)*LOG2E;
    A1L = lbn[c1]*rsqrtf(lbn[72+c1]+EPSF)*LOG2E;
    A2L = lbn[c2]*rsqrtf(lbn[72+c2]+EPSF)*LOG2E;
  }
  float A0g = (fabsf(A0L) > 1e-25f) ? A0L : copysignf(1e-25f, A0L);
  float ratio = A2L / A0g;

  size_t kvbase = ((size_t)n*8 + hd)*LEN;
  for (int i = t; i < LEN; i += T) {
    uint2 kk = kvK[kvbase + i];
    uint4 vv = kvV[kvbase + i];
    f32x4 kt; kt.x=bflo(kk.x)*A0g; kt.y=bfhi(kk.x)*A0g; kt.z=bflo(kk.y)*A0g; kt.w=bfhi(kk.y)*A0g;
    sKt[i] = kt;
    f32x4 va; va.x=bflo(vv.x); va.y=bfhi(vv.x); va.z=bflo(vv.y); va.w=bfhi(vv.y);
    sVa[i] = va;
    f32x4 vb; vb.x=bflo(vv.z); vb.y=bfhi(vv.z); vb.z=bflo(vv.w); vb.w=bfhi(vv.w);
    sVb[i] = vb;
  }
  for (int j = t; j < NJ; j += T) {
    uint4 a = rqk[j];
    uint4 sq;
    sq.x = pk2(bflo(a.x)*A1L,   bfhi(a.x)*A1L);
    sq.y = pk2(bflo(a.y)*A1L,   bfhi(a.y)*A1L);
    sq.z = pk2(bflo(a.z)*ratio, bfhi(a.z)*ratio);
    sq.w = pk2(bflo(a.w)*ratio, bfhi(a.w)*ratio);
    int r = j & 3, mm = j >> 2;
    tQK[r*NJ4 + mm] = sq;
    tVE[r*NJ4 + mm] = rve[j];
  }

  int g  = t / XT;
  int tl = t % XT;
  int y0 = g * YR;
  int x0 = 4 * tl;

  f32x4 q[4];
  #pragma unroll
  for (int i = 0; i < 4; ++i)
    q[i] = *(const f32x4*)(qb + (kvbase + x0 + i)*4);

  float m[4], ss[4];
  Acc acc[4];
  #pragma unroll
  for (int i=0;i<4;++i){ m[i]=-3.0e38f; ss[i]=0.f;
    #pragma unroll
    for(int d=0;d<4;++d){ acc[i].a[d].x=0.f; acc[i].a[d].y=0.f; } }

  __syncthreads();

  // window prologue: (y0 + LEN-1) & 3 == 3 always (LEN-1 = 3 mod 4, y0 = 0 mod 4)
  int mi = ((y0 + LEN-1) >> 2) - tl;
  uint4 wq0 = tQK[0*NJ4 + mi], wq1 = tQK[1*NJ4 + mi], wq2 = tQK[2*NJ4 + mi];
  uint4 wv0 = tVE[0*NJ4 + mi], wv1 = tVE[1*NJ4 + mi], wv2 = tVE[2*NJ4 + mi];

  for (int cc = 0; cc < YR/4; ++cc) {
    int yb = y0 + 4*cc;
    int ma = mi + cc;
    int mb = ma + 1;
    float lr[4][4];
    // ---- pass A (parities 3,0,1,2) ----
    uint4 e3 = tQK[3*NJ4 + ma];
    { f32x4 kt = sKt[yb];
      lr[0][0]=pairA(q[0],e3,kt);  lr[1][0]=pairA(q[1],wq2,kt);
      lr[2][0]=pairA(q[2],wq1,kt); lr[3][0]=pairA(q[3],wq0,kt); }
    uint4 e0 = tQK[0*NJ4 + mb];
    { f32x4 kt = sKt[yb+1];
      lr[0][1]=pairA(q[0],e0,kt);  lr[1][1]=pairA(q[1],e3,kt);
      lr[2][1]=pairA(q[2],wq2,kt); lr[3][1]=pairA(q[3],wq1,kt); }
    uint4 e1 = tQK[1*NJ4 + mb];
    { f32x4 kt = sKt[yb+2];
      lr[0][2]=pairA(q[0],e1,kt);  lr[1][2]=pairA(q[1],e0,kt);
      lr[2][2]=pairA(q[2],e3,kt);  lr[3][2]=pairA(q[3],wq2,kt); }
    uint4 e2v = tQK[2*NJ4 + mb];
    { f32x4 kt = sKt[yb+3];
      lr[0][3]=pairA(q[0],e2v,kt); lr[1][3]=pairA(q[1],e1,kt);
      lr[2][3]=pairA(q[2],e0,kt);  lr[3][3]=pairA(q[3],e3,kt); }
    wq0 = e0; wq1 = e1; wq2 = e2v;
    // ---- branchless chunk rescale ----
    #pragma unroll
    for (int i = 0; i < 4; ++i) {
      float cm = fmaxf(fmaxf(lr[i][0], lr[i][1]), fmaxf(lr[i][2], lr[i][3]));
      float mn = fmaxf(m[i], cm);
      float sc = __builtin_amdgcn_exp2f(m[i] - mn);
      m[i] = mn; ss[i] *= sc;
      f32x2 sc2; sc2.x = sc; sc2.y = sc;
      #pragma unroll
      for (int d = 0; d < 4; ++d) acc[i].a[d] *= sc2;
    }
    // ---- pass B (same window schedule) ----
    uint4 f3 = tVE[3*NJ4 + ma];
    { f32x4 va = sVa[yb], vb = sVb[yb];
      pairB(__builtin_amdgcn_exp2f(lr[0][0]-m[0]), f3,  va, vb, acc[0], ss[0]);
      pairB(__builtin_amdgcn_exp2f(lr[1][0]-m[1]), wv2, va, vb, acc[1], ss[1]);
      pairB(__builtin_amdgcn_exp2f(lr[2][0]-m[2]), wv1, va, vb, acc[2], ss[2]);
      pairB(__builtin_amdgcn_exp2f(lr[3][0]-m[3]), wv0, va, vb, acc[3], ss[3]); }
    uint4 f0 = tVE[0*NJ4 + mb];
    { f32x4 va = sVa[yb+1], vb = sVb[yb+1];
      pairB(__builtin_amdgcn_exp2f(lr[0][1]-m[0]), f0,  va, vb, acc[0], ss[0]);
      pairB(__builtin_amdgcn_exp2f(lr[1][1]-m[1]), f3,  va, vb, acc[1], ss[1]);
      pairB(__builtin_amdgcn_exp2f(lr[2][1]-m[2]), wv2, va, vb, acc[2], ss[2]);
      pairB(__builtin_amdgcn_exp2f(lr[3][1]-m[3]), wv1, va, vb, acc[3], ss[3]); }
    uint4 f1 = tVE[1*NJ4 + mb];
    { f32x4 va = sVa[yb+2], vb = sVb[yb+2];
      pairB(__builtin_amdgcn_exp2f(lr[0][2]-m[0]), f1,  va, vb, acc[0], ss[0]);
      pairB(__builtin_amdgcn_exp2f(lr[1][2]-m[1]), f0,  va, vb, acc[1], ss[1]);
      pairB(__builtin_amdgcn_exp2f(lr[2][2]-m[2]), f3,  va, vb, acc[2], ss[2]);
      pairB(__builtin_amdgcn_exp2f(lr[3][2]-m[3]), wv2, va, vb, acc[3], ss[3]); }
    uint4 f2v = tVE[2*NJ4 + mb];
    { f32x4 va = sVa[yb+3], vb = sVb[yb+3];
      pairB(__builtin_amdgcn_exp2f(lr[0][3]-m[0]), f2v, va, vb, acc[0], ss[0]);
      pairB(__builtin_amdgcn_exp2f(lr[1][3]-m[1]), f1,  va, vb, acc[1], ss[1]);
      pairB(__builtin_amdgcn_exp2f(lr[2][3]-m[2]), f0,  va, vb, acc[2], ss[2]);
      pairB(__builtin_amdgcn_exp2f(lr[3][3]-m[3]), f3,  va, vb, acc[3], ss[3]); }
    wv0 = f0; wv1 = f1; wv2 = f2v;
  }

  // ---- G-way merge via LDS ----
  __syncthreads();
  float4* M0 = (float4*)(pool);
  float4* M1 = (float4*)(pool + (size_t)(G-1)*LEN*16);
  float2* MS = (float2*)(pool + (size_t)(G-1)*LEN*32);
  if (g > 0) {
    #pragma unroll
    for (int i = 0; i < 4; ++i) {
      int slot = (g-1)*LEN + x0 + i;
      M0[slot] = make_float4(acc[i].a[0].x,acc[i].a[0].y,acc[i].a[1].x,acc[i].a[1].y);
      M1[slot] = make_float4(acc[i].a[2].x,acc[i].a[2].y,acc[i].a[3].x,acc[i].a[3].y);
      MS[slot] = make_float2(m[i], ss[i]);
    }
  }
  __syncthreads();
  if (g == 0) {
    #pragma unroll
    for (int i = 0; i < 4; ++i) {
      float M = m[i];
      float2 oms[G-1];
      #pragma unroll
      for (int gg = 1; gg < G; ++gg) {
        oms[gg-1] = MS[(gg-1)*LEN + x0 + i];
        M = fmaxf(M, oms[gg-1].x);
      }
      float w0 = __builtin_amdgcn_exp2f(m[i] - M);
      float st = ss[i]*w0;
      float a[8];
      a[0]=acc[i].a[0].x*w0; a[1]=acc[i].a[0].y*w0; a[2]=acc[i].a[1].x*w0; a[3]=acc[i].a[1].y*w0;
      a[4]=acc[i].a[2].x*w0; a[5]=acc[i].a[2].y*w0; a[6]=acc[i].a[3].x*w0; a[7]=acc[i].a[3].y*w0;
      #pragma unroll
      for (int gg = 1; gg < G; ++gg) {
        int slot = (gg-1)*LEN + x0 + i;
        float wg = __builtin_amdgcn_exp2f(oms[gg-1].x - M);
        st += oms[gg-1].y*wg;
        float4 a0 = M0[slot];
        float4 a1 = M1[slot];
        a[0] = fmaf(a0.x, wg, a[0]); a[1] = fmaf(a0.y, wg, a[1]);
        a[2] = fmaf(a0.z, wg, a[2]); a[3] = fmaf(a0.w, wg, a[3]);
        a[4] = fmaf(a1.x, wg, a[4]); a[5] = fmaf(a1.y, wg, a[5]);
        a[6] = fmaf(a1.z, wg, a[6]); a[7] = fmaf(a1.w, wg, a[7]);
      }
      float inv = 1.0f / st;
      float* dst = out + ((size_t)(x0+i)*XS + (size_t)n*NS)*64 + hd*8;
      float4 lo, hi;
      lo.x = a[0]*inv; lo.y = a[1]*inv; lo.z = a[2]*inv; lo.w = a[3]*inv;
      hi.x = a[4]*inv; hi.y = a[5]*inv; hi.z = a[6]*inv; hi.w = a[7]*inv;
      if (RELUO) {
        lo.x=fmaxf(lo.x,0.f); lo.y=fmaxf(lo.y,0.f); lo.z=fmaxf(lo.z,0.f); lo.w=fmaxf(lo.w,0.f);
        hi.x=fmaxf(hi.x,0.f); hi.y=fmaxf(hi.y,0.f); hi.z=fmaxf(hi.z,0.f); hi.w=fmaxf(hi.w,0.f);
      }
      *(float4*)dst = lo;
      *((float4*)dst + 1) = hi;
    }
  }
}

// ---------------- conv3 + bn + residual + relu : NHWC in -> NCHW out ----------------
__global__ __launch_bounds__(256)
void k_conv3(const float* __restrict__ in, const float* __restrict__ w,
             const float* __restrict__ bn, const float* __restrict__ resid,
             float* __restrict__ out) {
  __shared__ float L[64*65];
  int tid = threadIdx.x;
  int p0 = blockIdx.x * 64;
  const float4* src = (const float4*)(in + (size_t)p0*64);
  #pragma unroll
  for (int k = 0; k < 4; ++k) {
    int f4 = tid + k*256;
    float4 v = src[f4];
    int f = f4*4; int p = f >> 6, o = f & 63;
    L[p*65+o] = v.x; L[p*65+o+1] = v.y; L[p*65+o+2] = v.z; L[p*65+o+3] = v.w;
  }
  __syncthreads();
  int lane = tid & 63;
  int wvs = __builtin_amdgcn_readfirstlane(tid >> 6);
  f32x2 xv2[32];
  #pragma unroll
  for (int c2 = 0; c2 < 32; ++c2) {
    xv2[c2].x = L[lane*65 + 2*c2];
    xv2[c2].y = L[lane*65 + 2*c2 + 1];
  }
  #pragma unroll
  for (int r = 0; r < 16; ++r) {
    int o = wvs*16 + r;
    const f32x2* wr = (const f32x2*)(w + o*64);
    f32x2 a2 = {0.f, 0.f};
    #pragma unroll
    for (int c2 = 0; c2 < 32; ++c2) a2 = wr[c2]*xv2[c2] + a2;
    float acc = a2.x + a2.y;
    float s = bn[o] * rsqrtf(bn[192+o] + EPSF);
    float val = fmaf(acc, s, fmaf(-bn[128+o], s, bn[64+o]));
    size_t idx = (size_t)o*32768 + p0 + lane;
    out[idx] = fmaxf(val + resid[idx], 0.f);
  }
}

extern "C" void kernel_launch(void* const* d_in, const int* in_sizes, int n_in,
                              void* d_out, int out_size, void* d_ws, size_t ws_size,
                              hipStream_t stream) {
  const float* x         = (const float*)d_in[0];
  const float* conv1_w   = (const float*)d_in[1];
  const float* bn1       = (const float*)d_in[2];
  const float* kqv_w_h   = (const float*)d_in[3];
  const float* kqv_bn_h  = (const float*)d_in[4];
  const float* lbn_h     = (const float*)d_in[5];
  const float* rel_h     = (const float*)d_in[6];
  const float* kqv_w_w   = (const float*)d_in[7];
  const float* kqv_bn_w  = (const float*)d_in[8];
  const float* lbn_w     = (const float*)d_in[9];
  const float* rel_w     = (const float*)d_in[10];
  const float* conv3_w   = (const float*)d_in[11];
  const float* bn3       = (const float*)d_in[12];
  float* outp = (float*)d_out;
  char* ws = (char*)d_ws;

  float* A    = (float*)(ws);                    // 8 MiB
  uint4* kvV  = (uint4*)(ws + 8388608);          // 4 MiB
  uint2* kvK  = (uint2*)(ws + 12582912);         // 2 MiB
  float* qb   = (float*)(ws + 14680064);         // 4 MiB (f32 q)
  uint4* rqkH = (uint4*)(ws + 18874368);
  uint4* rveH = (uint4*)(ws + 18882560);
  uint4* rqkW = (uint4*)(ws + 18890752);
  uint4* rveW = (uint4*)(ws + 18894848);

  k_relpack<<<2, 512, 0, stream>>>(rel_h, rel_w, rqkH, rveH, rqkW, rveW);

  // conv1 + bn1 + relu : x NCHW -> A NHWC
  k_conv1<<<512, 256, 0, stream>>>(x, conv1_w, bn1, A);

  // axial-H: n = w (128), seq = h (256); G=4, XB=4 -> 256 thr
  k_kqv<256,128,1><<<dim3(128,4), 512, 0, stream>>>(A, kqv_w_h, kqv_bn_h, kvV, kvK, qb);
  k_attn4<256,4,false,128,1><<<1024, 256, 0, stream>>>(kvV, kvK, qb, rqkH, rveH, lbn_h, A);

  // axial-W: n = h (256), seq = w (128); G=4, XB=4 -> 128 thr; relu fused
  k_kqv<128,1,128><<<dim3(256,2), 512, 0, stream>>>(A, kqv_w_w, kqv_bn_w, kvV, kvK, qb);
  k_attn4<128,4,true,1,128><<<2048, 128, 0, stream>>>(kvV, kvK, qb, rqkW, rveW, lbn_w, A);

  // conv3 + bn3 + residual + relu : A NHWC -> out NCHW
  k_conv3<<<512, 256, 0, stream>>>(A, conv3_w, bn3, x, outp);
}